// Round 1
// baseline (132.632 us; speedup 1.0000x reference)
//
#include <hip/hip_runtime.h>

// Masked attention, b=8 n=m=4096 d=dv=64, f32 in/out.
// Flash-attention w/ swapped QK^T, 32x32x16 bf16 MFMA, key-split across wave pairs.

#define B_ 8
#define N_ 4096
#define M_ 4096
#define D_ 64

typedef __attribute__((ext_vector_type(8))) __bf16 bfrag;
typedef __attribute__((ext_vector_type(16))) float f32x16;
typedef __attribute__((ext_vector_type(4))) float f32x4;

union FragU { bfrag f; unsigned int u[4]; };

__device__ __forceinline__ unsigned int pkbf(float lo, float hi) {
  unsigned short a = __builtin_bit_cast(unsigned short, (__bf16)lo);
  unsigned short b = __builtin_bit_cast(unsigned short, (__bf16)hi);
  return ((unsigned int)b << 16) | (unsigned int)a;
}
__device__ __forceinline__ unsigned short bf1(float x) {
  return __builtin_bit_cast(unsigned short, (__bf16)x);
}
// XOR-swizzle: row = byte>>7 (128B rows), flip 16B slot by row&7 (G4 fix)
__device__ __forceinline__ unsigned int swz(unsigned int byte) {
  return byte ^ (((byte >> 7) & 7) << 4);
}

// LDS layout (bytes):
//   0     : K tiles      [2 halves][64 keys][64 d] bf16, swizzled   (16384)
//   16384 : Vt tiles     [2 halves][64 dv][64 keys] bf16, swizzled  (16384)
//   32768 : key bias     [2][64] f32                                 (512)
//   33280 : alpha bounce [4 waves][32] f32                           (512)
//   33792 : merge m      [2][32] f32                                 (256)
//   34048 : merge l      [2][32] f32                                 (256)
//   34304 : merge c0*il  [2][32] f32                                 (256)
//   34560 : merge c1*il  [2][32] f32                                 (256)
//   (merge O reuses K region: [2][32 rows][64] f32 = 16384)

__global__ __launch_bounds__(256, 2) void attn_fused(
    const float* __restrict__ qg, const float* __restrict__ kg,
    const float* __restrict__ vg, const int* __restrict__ mqg,
    const int* __restrict__ mkg, float* __restrict__ outg)
{
  __shared__ alignas(16) char smem[35072];
  const int tid  = threadIdx.x;
  const int lane = tid & 63;
  const int lq   = lane & 31;   // q-col (QK) / dv-col (PV)
  const int lh   = lane >> 5;   // k-half of MFMA operands
  const int wid  = tid >> 6;    // 0..3
  const int khalf = wid >> 1;   // which 2048-key half this wave reduces
  const int qrw  = (wid & 1) * 32;
  const int batch = blockIdx.x & 7;
  const int qbase = (blockIdx.x >> 3) * 64;

  char* Kl = smem + khalf * 8192;
  char* Vl = smem + 16384 + khalf * 8192;
  float* kbf    = (float*)(smem + 32768);
  float* alphav = (float*)(smem + 33280);
  float* mM     = (float*)(smem + 33792);
  float* mL     = (float*)(smem + 34048);
  float* bC0    = (float*)(smem + 34304);
  float* bC1    = (float*)(smem + 34560);

  // ---- Q load: pre-scale by mask_query * log2(e)/8 (folds temp+qmask+exp2) ----
  const int grow = qbase + qrw + lq;
  const float qs = mqg[batch * N_ + grow] ? 0.1803368801111204f : 0.0f;
  bfrag qf[4];
  {
    const float* Qp = qg + ((size_t)batch * N_ + grow) * D_ + lh * 8;
#pragma unroll
    for (int c = 0; c < 4; ++c) {
      float4 a = *(const float4*)(Qp + c * 16);
      float4 b = *(const float4*)(Qp + c * 16 + 4);
      FragU f;
      f.u[0] = pkbf(a.x * qs, a.y * qs);
      f.u[1] = pkbf(a.z * qs, a.w * qs);
      f.u[2] = pkbf(b.x * qs, b.y * qs);
      f.u[3] = pkbf(b.z * qs, b.w * qs);
      qf[c] = f.f;
    }
  }

  const int sid   = tid & 127;  // id within staging half-group
  const int shalf = tid >> 7;   // which half this thread stages

  f32x16 o0, o1;
#pragma unroll
  for (int i = 0; i < 16; ++i) { o0[i] = 0.f; o1[i] = 0.f; }
  float m2 = -1e30f, lsum = 0.f;

  for (int t = 0; t < 32; ++t) {
    __syncthreads();  // previous tile fully consumed
    // ---- stage K (swizzled), V (transposed+swizzled), key bias ----
    {
      const int kb0 = shalf * 2048 + t * 64;
      const float4* K4 = (const float4*)(kg + ((size_t)batch * M_ + kb0) * D_);
      const float4* V4 = (const float4*)(vg + ((size_t)batch * M_ + kb0) * D_);
      char* Ks = smem + shalf * 8192;
      char* Vs = smem + 16384 + shalf * 8192;
#pragma unroll
      for (int j = 0; j < 8; ++j) {
        int idx = sid + j * 128;                 // float4 index, 0..1023
        float4 a = K4[idx];
        int row = idx >> 4, col = (idx & 15) << 2;
        *(uint2*)(Ks + swz((unsigned)(row * 128 + col * 2))) =
            make_uint2(pkbf(a.x, a.y), pkbf(a.z, a.w));
        float4 b = V4[idx];
        int vk = idx >> 4, vc = (idx & 15) << 2;
        *(unsigned short*)(Vs + swz((unsigned)((vc + 0) * 128 + vk * 2))) = bf1(b.x);
        *(unsigned short*)(Vs + swz((unsigned)((vc + 1) * 128 + vk * 2))) = bf1(b.y);
        *(unsigned short*)(Vs + swz((unsigned)((vc + 2) * 128 + vk * 2))) = bf1(b.z);
        *(unsigned short*)(Vs + swz((unsigned)((vc + 3) * 128 + vk * 2))) = bf1(b.w);
      }
      if (sid < 64)
        kbf[shalf * 64 + sid] = mkg[batch * M_ + kb0 + sid] ? 0.f : -1e30f;
    }
    __syncthreads();

    // ---- swapped QK^T: S^T[key][q] = K · Q^T  (rows lane-local after this) ----
    f32x16 s0, s1;
#pragma unroll
    for (int i = 0; i < 16; ++i) { s0[i] = 0.f; s1[i] = 0.f; }
#pragma unroll
    for (int c = 0; c < 4; ++c) {
      bfrag kf0 = *(const bfrag*)(Kl + swz((unsigned)(lq * 128 + (c * 16 + lh * 8) * 2)));
      bfrag kf1 = *(const bfrag*)(Kl + swz((unsigned)((32 + lq) * 128 + (c * 16 + lh * 8) * 2)));
      s0 = __builtin_amdgcn_mfma_f32_32x32x16_bf16(kf0, qf[c], s0, 0, 0, 0);
      s1 = __builtin_amdgcn_mfma_f32_32x32x16_bf16(kf1, qf[c], s1, 0, 0, 0);
    }

    // ---- key-mask bias + row max (in-register; 1 shfl to combine halves) ----
    const float* kbh = kbf + khalf * 64;
    float mx = -1e30f;
#pragma unroll
    for (int g = 0; g < 4; ++g) {
      f32x4 b0 = *(const f32x4*)(kbh + g * 8 + 4 * lh);
      f32x4 b1 = *(const f32x4*)(kbh + 32 + g * 8 + 4 * lh);
#pragma unroll
      for (int r = 0; r < 4; ++r) {
        s0[g * 4 + r] += b0[r];
        s1[g * 4 + r] += b1[r];
        mx = fmaxf(mx, fmaxf(s0[g * 4 + r], s1[g * 4 + r]));
      }
    }
    mx = fmaxf(mx, __shfl_xor(mx, 32));

    // ---- defer-max rescale (T13, THR=8 in log2 units) ----
    if (__any(mx > m2 + 8.f)) {
      float mn = fmaxf(m2, mx);
      float al = __builtin_amdgcn_exp2f(m2 - mn);
      if (lane < 32) alphav[wid * 32 + lane] = al;
      asm volatile("s_waitcnt lgkmcnt(0)" ::: "memory");
#pragma unroll
      for (int g = 0; g < 4; ++g) {
        f32x4 av = *(const f32x4*)(alphav + wid * 32 + g * 8 + 4 * lh);
#pragma unroll
        for (int r = 0; r < 4; ++r) { o0[g * 4 + r] *= av[r]; o1[g * 4 + r] *= av[r]; }
      }
      lsum *= al;
      m2 = mn;
    }

    // ---- p = exp2(logit - m), running sum ----
    float ps = 0.f;
#pragma unroll
    for (int i = 0; i < 16; ++i) {
      float p0 = __builtin_amdgcn_exp2f(s0[i] - m2);
      float p1 = __builtin_amdgcn_exp2f(s1[i] - m2);
      s0[i] = p0; s1[i] = p1;
      ps += p0 + p1;
    }
    ps += __shfl_xor(ps, 32);
    lsum += ps;

    // ---- P·V: assemble A-frags (cvt_pk + cross-half shfl), MFMA ----
#pragma unroll
    for (int mc = 0; mc < 4; ++mc) {
      unsigned int c01, c23, c45, c67;
      {
        const int Rb = (mc & 1) * 8;
        if (mc < 2) {
          c01 = pkbf(s0[Rb + 0], s0[Rb + 1]); c23 = pkbf(s0[Rb + 2], s0[Rb + 3]);
          c45 = pkbf(s0[Rb + 4], s0[Rb + 5]); c67 = pkbf(s0[Rb + 6], s0[Rb + 7]);
        } else {
          c01 = pkbf(s1[Rb + 0], s1[Rb + 1]); c23 = pkbf(s1[Rb + 2], s1[Rb + 3]);
          c45 = pkbf(s1[Rb + 4], s1[Rb + 5]); c67 = pkbf(s1[Rb + 6], s1[Rb + 7]);
        }
      }
      unsigned int t01 = (unsigned int)__shfl_xor((int)c01, 32);
      unsigned int t23 = (unsigned int)__shfl_xor((int)c23, 32);
      unsigned int t45 = (unsigned int)__shfl_xor((int)c45, 32);
      unsigned int t67 = (unsigned int)__shfl_xor((int)c67, 32);
      FragU pa;
      pa.u[0] = lh ? t45 : c01;
      pa.u[1] = lh ? t67 : c23;
      pa.u[2] = lh ? c45 : t01;
      pa.u[3] = lh ? c67 : t23;
      bfrag vf0 = *(const bfrag*)(Vl + swz((unsigned)(lq * 128 + (mc * 16 + lh * 8) * 2)));
      bfrag vf1 = *(const bfrag*)(Vl + swz((unsigned)((32 + lq) * 128 + (mc * 16 + lh * 8) * 2)));
      o0 = __builtin_amdgcn_mfma_f32_32x32x16_bf16(pa.f, vf0, o0, 0, 0, 0);
      o1 = __builtin_amdgcn_mfma_f32_32x32x16_bf16(pa.f, vf1, o1, 0, 0, 0);
    }
  }

  // ---- merge the two key-halves, divide by l, store ----
  __syncthreads();
  float* Omg = (float*)smem;  // reuse K region: [2][32][64] f32
  if (khalf == 1) {
    const int w = wid & 1;
    if (lane < 32) { mM[w * 32 + lane] = m2; mL[w * 32 + lane] = lsum; }
#pragma unroll
    for (int r = 0; r < 16; ++r) {
      const int row = (r & 3) + 8 * (r >> 2) + 4 * lh;
      Omg[w * 2048 + row * 64 + lq]      = o0[r];
      Omg[w * 2048 + row * 64 + 32 + lq] = o1[r];
    }
  }
  __syncthreads();
  if (khalf == 0) {
    const int w = wid & 1;
    float m1 = mM[w * 32 + lq], l1 = mL[w * 32 + lq];
    float msf = fmaxf(m2, m1);
    float c0 = __builtin_amdgcn_exp2f(m2 - msf);
    float c1 = __builtin_amdgcn_exp2f(m1 - msf);
    float il = 1.f / (lsum * c0 + l1 * c1);
    if (lane < 32) { bC0[w * 32 + lane] = c0 * il; bC1[w * 32 + lane] = c1 * il; }
    asm volatile("s_waitcnt lgkmcnt(0)" ::: "memory");
    float* outp = outg + ((size_t)batch * N_ + qbase + qrw) * 64;
#pragma unroll
    for (int g = 0; g < 4; ++g) {
      f32x4 a0 = *(const f32x4*)(bC0 + w * 32 + g * 8 + 4 * lh);
      f32x4 a1 = *(const f32x4*)(bC1 + w * 32 + g * 8 + 4 * lh);
#pragma unroll
      for (int rr = 0; rr < 4; ++rr) {
        const int r = g * 4 + rr;
        const int row = rr + 8 * g + 4 * lh;
        float r0 = o0[r] * a0[rr] + Omg[w * 2048 + row * 64 + lq]      * a1[rr];
        float r1 = o1[r] * a0[rr] + Omg[w * 2048 + row * 64 + 32 + lq] * a1[rr];
        outp[(size_t)row * 64 + lq]      = r0;
        outp[(size_t)row * 64 + 32 + lq] = r1;
      }
    }
  }
}

extern "C" void kernel_launch(void* const* d_in, const int* in_sizes, int n_in,
                              void* d_out, int out_size, void* d_ws, size_t ws_size,
                              hipStream_t stream) {
  const float* q  = (const float*)d_in[0];
  const float* k  = (const float*)d_in[1];
  const float* v  = (const float*)d_in[2];
  const int*   mq = (const int*)d_in[3];
  const int*   mk = (const int*)d_in[4];
  float* out = (float*)d_out;
  attn_fused<<<dim3(512), dim3(256), 0, stream>>>(q, k, v, mq, mk, out);
}

// Round 2
// 81.509 us; speedup vs baseline: 1.6272x; 1.6272x over previous
//
#include <hip/hip_runtime.h>

// Masked attention, b=8 n=m=4096 d=dv=64, f32 in/out.
// R2: prepass packs K (bf16) and V^T (bf16) into swizzled 8KB LDS tile images in
// d_ws; main kernel double-buffers tiles via global_load_lds with counted vmcnt.

#define B_ 8
#define N_ 4096
#define M_ 4096
#define D_ 64

typedef __attribute__((ext_vector_type(8))) __bf16 bfrag;
typedef __attribute__((ext_vector_type(16))) float f32x16;
typedef __attribute__((ext_vector_type(4))) float f32x4;

union FragU { bfrag f; unsigned int u[4]; };

__device__ __forceinline__ unsigned int pkbf(float lo, float hi) {
  unsigned short a = __builtin_bit_cast(unsigned short, (__bf16)lo);
  unsigned short b = __builtin_bit_cast(unsigned short, (__bf16)hi);
  return ((unsigned int)b << 16) | (unsigned int)a;
}
__device__ __forceinline__ unsigned short bf1(float x) {
  return __builtin_bit_cast(unsigned short, (__bf16)x);
}
// XOR-swizzle: 128B rows, flip 16B slot by row&7 (16B chunks move as units)
__device__ __forceinline__ unsigned int swz(unsigned int byte) {
  return byte ^ (((byte >> 7) & 7) << 4);
}

__device__ __forceinline__ void gload16(const void* g, void* l) {
  __builtin_amdgcn_global_load_lds((const __attribute__((address_space(1))) void*)g,
                                   (__attribute__((address_space(3))) void*)l, 16, 0, 0);
}
__device__ __forceinline__ void gload4(const void* g, void* l) {
  __builtin_amdgcn_global_load_lds((const __attribute__((address_space(1))) void*)g,
                                   (__attribute__((address_space(3))) void*)l, 4, 0, 0);
}

#define WAITV(n) asm volatile("s_waitcnt vmcnt(" #n ")" ::: "memory")
#define BAR() asm volatile("s_barrier" ::: "memory")

// ---------------- prepass: build swizzled bf16 tile images in ws ----------------
// kws: [8][64 tiles][8192B]  image[swz(row*128 + d*2)] = bf16(K[tile*64+row][d])
// vws: [8][64 tiles][8192B]  image[swz(dv*128 + key*2)] = bf16(V[tile*64+key][dv])
// bws: [8][4096] f32         0 or -1e30 per key
__global__ void attn_prepass(const float* __restrict__ kg, const float* __restrict__ vg,
                             const int* __restrict__ mkg, char* __restrict__ kws,
                             char* __restrict__ vws, float* __restrict__ bws)
{
  const int bid = blockIdx.x, tid = threadIdx.x;
  if (bid < 1024) {
    const int c = bid * 256 + tid;            // K chunk id, 0..262143
    const int batch = c >> 15, cb = c & 32767;
    const int tile = cb >> 9, q = cb & 511;
    const int row = q >> 3, cg = q & 7;
    const float* src = kg + (((size_t)batch * M_ + tile * 64 + row) * D_ + cg * 8);
    float4 a = ((const float4*)src)[0], b = ((const float4*)src)[1];
    uint4 o;
    o.x = pkbf(a.x, a.y); o.y = pkbf(a.z, a.w);
    o.z = pkbf(b.x, b.y); o.w = pkbf(b.z, b.w);
    *(uint4*)(kws + ((size_t)(batch * 64 + tile)) * 8192 + swz((unsigned)(row * 128 + cg * 16))) = o;
    if (tid < 32) {
      const int i = bid * 32 + tid;           // 0..32767
      bws[i] = mkg[i] ? 0.f : -1e30f;
    }
  } else {
    const int c = (bid - 1024) * 256 + tid;   // V chunk id
    const int batch = c >> 15, cb = c & 32767;
    const int tile = cb >> 9, q = cb & 511;
    const int dv = q & 63, kgp = q >> 6;
    const float* base = vg + (((size_t)batch * M_ + tile * 64 + kgp * 8) * D_ + dv);
    unsigned short h[8];
#pragma unroll
    for (int j = 0; j < 8; ++j) h[j] = bf1(base[j * D_]);
    uint4 o;
    o.x = (unsigned)h[0] | ((unsigned)h[1] << 16);
    o.y = (unsigned)h[2] | ((unsigned)h[3] << 16);
    o.z = (unsigned)h[4] | ((unsigned)h[5] << 16);
    o.w = (unsigned)h[6] | ((unsigned)h[7] << 16);
    *(uint4*)(vws + ((size_t)(batch * 64 + tile)) * 8192 + swz((unsigned)(dv * 128 + kgp * 16))) = o;
  }
}

// ---------------- main kernel ----------------
// LDS: buf b in [0,2): K(b,half) at b*32768+half*16384, V at +8192
//   bias   65536 + (b*2+half)*256       [2][2][64] f32
//   alphav 66560 [4][32] f32
//   mM 67072  mL 67328  bC0 67584  bC1 67840   (each [2][32] f32)
//   merge O reuses [0,16384)
__global__ __launch_bounds__(256, 2) void attn_main(
    const float* __restrict__ qg, const int* __restrict__ mqg,
    const char* __restrict__ kws, const char* __restrict__ vws,
    const float* __restrict__ bws, float* __restrict__ outg)
{
  __shared__ alignas(16) char smem[68096];
  const int tid  = threadIdx.x;
  const int lane = tid & 63;
  const int lq   = lane & 31;
  const int lh   = lane >> 5;
  const int wid  = tid >> 6;
  const int khalf = wid >> 1;
  const int qrw  = (wid & 1) * 32;
  const int batch = blockIdx.x & 7;
  const int qbase = (blockIdx.x >> 3) * 64;

  float* alphav = (float*)(smem + 66560);
  float* mM     = (float*)(smem + 67072);
  float* mL     = (float*)(smem + 67328);
  float* bC0    = (float*)(smem + 67584);
  float* bC1    = (float*)(smem + 67840);

  // ---- Q load: pre-scale by mask_query * log2(e)/8 ----
  const int grow = qbase + qrw + lq;
  const float qs = mqg[batch * N_ + grow] ? 0.1803368801111204f : 0.0f;
  bfrag qf[4];
  {
    const float* Qp = qg + ((size_t)batch * N_ + grow) * D_ + lh * 8;
#pragma unroll
    for (int c = 0; c < 4; ++c) {
      float4 a = *(const float4*)(Qp + c * 16);
      float4 b = *(const float4*)(Qp + c * 16 + 4);
      FragU f;
      f.u[0] = pkbf(a.x * qs, a.y * qs);
      f.u[1] = pkbf(a.z * qs, a.w * qs);
      f.u[2] = pkbf(b.x * qs, b.y * qs);
      f.u[3] = pkbf(b.z * qs, b.w * qs);
      qf[c] = f.f;
    }
  }

  // ---- staging: K-wave (even wid) = K tile + bias; V-wave (odd) = V tile ----
  auto STAGE = [&](int buf, int t) {
    const size_t rec = ((size_t)(batch * 64 + khalf * 32 + t)) * 8192 + (size_t)lane * 16;
    if (!(wid & 1)) {
      const char* g = kws + rec;
      char* lp = smem + buf * 32768 + khalf * 16384;
#pragma unroll
      for (int i = 0; i < 8; ++i) gload16(g + i * 1024, lp + i * 1024);
      gload4(bws + batch * M_ + khalf * 2048 + t * 64 + lane,
             smem + 65536 + (buf * 2 + khalf) * 256);
    } else {
      const char* g = vws + rec;
      char* lp = smem + buf * 32768 + khalf * 16384 + 8192;
#pragma unroll
      for (int i = 0; i < 8; ++i) gload16(g + i * 1024, lp + i * 1024);
    }
  };

  f32x16 o0, o1;
#pragma unroll
  for (int i = 0; i < 16; ++i) { o0[i] = 0.f; o1[i] = 0.f; }
  float m2 = -1e30f, lsum = 0.f;

  STAGE(0, 0);
  int cur = 0;
  for (int t = 0; t < 32; ++t) {
    if (t < 31) {
      STAGE(cur ^ 1, t + 1);
      if (!(wid & 1)) { WAITV(9); } else { WAITV(8); }
    } else {
      WAITV(0);
    }
    BAR();

    const char* Kl = smem + cur * 32768 + khalf * 16384;
    const char* Vl = Kl + 8192;
    const float* kbh = (const float*)(smem + 65536 + (cur * 2 + khalf) * 256);

    // ---- swapped QK^T ----
    f32x16 s0, s1;
#pragma unroll
    for (int i = 0; i < 16; ++i) { s0[i] = 0.f; s1[i] = 0.f; }
#pragma unroll
    for (int c = 0; c < 4; ++c) {
      bfrag kf0 = *(const bfrag*)(Kl + swz((unsigned)(lq * 128 + (c * 16 + lh * 8) * 2)));
      bfrag kf1 = *(const bfrag*)(Kl + swz((unsigned)((32 + lq) * 128 + (c * 16 + lh * 8) * 2)));
      s0 = __builtin_amdgcn_mfma_f32_32x32x16_bf16(kf0, qf[c], s0, 0, 0, 0);
      s1 = __builtin_amdgcn_mfma_f32_32x32x16_bf16(kf1, qf[c], s1, 0, 0, 0);
    }

    // ---- key bias + row max ----
    float mx = -1e30f;
#pragma unroll
    for (int g = 0; g < 4; ++g) {
      f32x4 b0 = *(const f32x4*)(kbh + g * 8 + 4 * lh);
      f32x4 b1 = *(const f32x4*)(kbh + 32 + g * 8 + 4 * lh);
#pragma unroll
      for (int r = 0; r < 4; ++r) {
        s0[g * 4 + r] += b0[r];
        s1[g * 4 + r] += b1[r];
        mx = fmaxf(mx, fmaxf(s0[g * 4 + r], s1[g * 4 + r]));
      }
    }
    mx = fmaxf(mx, __shfl_xor(mx, 32));

    // ---- defer-max rescale (THR=8 log2 units) ----
    if (__any(mx > m2 + 8.f)) {
      float mn = fmaxf(m2, mx);
      float al = __builtin_amdgcn_exp2f(m2 - mn);
      if (lane < 32) alphav[wid * 32 + lane] = al;
      asm volatile("s_waitcnt lgkmcnt(0)" ::: "memory");
#pragma unroll
      for (int g = 0; g < 4; ++g) {
        f32x4 av = *(const f32x4*)(alphav + wid * 32 + g * 8 + 4 * lh);
#pragma unroll
        for (int r = 0; r < 4; ++r) { o0[g * 4 + r] *= av[r]; o1[g * 4 + r] *= av[r]; }
      }
      lsum *= al;
      m2 = mn;
    }

    // ---- p = exp2(logit - m), running sum ----
    float ps = 0.f;
#pragma unroll
    for (int i = 0; i < 16; ++i) {
      float p0 = __builtin_amdgcn_exp2f(s0[i] - m2);
      float p1 = __builtin_amdgcn_exp2f(s1[i] - m2);
      s0[i] = p0; s1[i] = p1;
      ps += p0 + p1;
    }
    ps += __shfl_xor(ps, 32);
    lsum += ps;

    // ---- P·V ----
#pragma unroll
    for (int mc = 0; mc < 4; ++mc) {
      unsigned int c01, c23, c45, c67;
      {
        const int Rb = (mc & 1) * 8;
        if (mc < 2) {
          c01 = pkbf(s0[Rb + 0], s0[Rb + 1]); c23 = pkbf(s0[Rb + 2], s0[Rb + 3]);
          c45 = pkbf(s0[Rb + 4], s0[Rb + 5]); c67 = pkbf(s0[Rb + 6], s0[Rb + 7]);
        } else {
          c01 = pkbf(s1[Rb + 0], s1[Rb + 1]); c23 = pkbf(s1[Rb + 2], s1[Rb + 3]);
          c45 = pkbf(s1[Rb + 4], s1[Rb + 5]); c67 = pkbf(s1[Rb + 6], s1[Rb + 7]);
        }
      }
      unsigned int t01 = (unsigned int)__shfl_xor((int)c01, 32);
      unsigned int t23 = (unsigned int)__shfl_xor((int)c23, 32);
      unsigned int t45 = (unsigned int)__shfl_xor((int)c45, 32);
      unsigned int t67 = (unsigned int)__shfl_xor((int)c67, 32);
      FragU pa;
      pa.u[0] = lh ? t45 : c01;
      pa.u[1] = lh ? t67 : c23;
      pa.u[2] = lh ? c45 : t01;
      pa.u[3] = lh ? c67 : t23;
      bfrag vf0 = *(const bfrag*)(Vl + swz((unsigned)(lq * 128 + (mc * 16 + lh * 8) * 2)));
      bfrag vf1 = *(const bfrag*)(Vl + swz((unsigned)((32 + lq) * 128 + (mc * 16 + lh * 8) * 2)));
      o0 = __builtin_amdgcn_mfma_f32_32x32x16_bf16(pa.f, vf0, o0, 0, 0, 0);
      o1 = __builtin_amdgcn_mfma_f32_32x32x16_bf16(pa.f, vf1, o1, 0, 0, 0);
    }

    BAR();
    cur ^= 1;
  }

  // ---- merge key-halves, divide by l, store ----
  __syncthreads();
  float* Omg = (float*)smem;  // [2][32][64] f32
  if (khalf == 1) {
    const int w = wid & 1;
    if (lane < 32) { mM[w * 32 + lane] = m2; mL[w * 32 + lane] = lsum; }
#pragma unroll
    for (int r = 0; r < 16; ++r) {
      const int row = (r & 3) + 8 * (r >> 2) + 4 * lh;
      Omg[w * 2048 + row * 64 + lq]      = o0[r];
      Omg[w * 2048 + row * 64 + 32 + lq] = o1[r];
    }
  }
  __syncthreads();
  if (khalf == 0) {
    const int w = wid & 1;
    float m1 = mM[w * 32 + lq], l1 = mL[w * 32 + lq];
    float msf = fmaxf(m2, m1);
    float c0 = __builtin_amdgcn_exp2f(m2 - msf);
    float c1 = __builtin_amdgcn_exp2f(m1 - msf);
    float il = 1.f / (lsum * c0 + l1 * c1);
    if (lane < 32) { bC0[w * 32 + lane] = c0 * il; bC1[w * 32 + lane] = c1 * il; }
    asm volatile("s_waitcnt lgkmcnt(0)" ::: "memory");
    float* outp = outg + ((size_t)batch * N_ + qbase + qrw) * 64;
#pragma unroll
    for (int g = 0; g < 4; ++g) {
      f32x4 a0 = *(const f32x4*)(bC0 + w * 32 + g * 8 + 4 * lh);
      f32x4 a1 = *(const f32x4*)(bC1 + w * 32 + g * 8 + 4 * lh);
#pragma unroll
      for (int rr = 0; rr < 4; ++rr) {
        const int r = g * 4 + rr;
        const int row = rr + 8 * g + 4 * lh;
        float r0 = o0[r] * a0[rr] + Omg[w * 2048 + row * 64 + lq]      * a1[rr];
        float r1 = o1[r] * a0[rr] + Omg[w * 2048 + row * 64 + 32 + lq] * a1[rr];
        outp[(size_t)row * 64 + lq]      = r0;
        outp[(size_t)row * 64 + 32 + lq] = r1;
      }
    }
  }
}

// ---------------- fallback (R1, verified): used if ws too small ----------------
__global__ __launch_bounds__(256, 2) void attn_fused(
    const float* __restrict__ qg, const float* __restrict__ kg,
    const float* __restrict__ vg, const int* __restrict__ mqg,
    const int* __restrict__ mkg, float* __restrict__ outg)
{
  __shared__ alignas(16) char smem[35072];
  const int tid  = threadIdx.x;
  const int lane = tid & 63;
  const int lq   = lane & 31;
  const int lh   = lane >> 5;
  const int wid  = tid >> 6;
  const int khalf = wid >> 1;
  const int qrw  = (wid & 1) * 32;
  const int batch = blockIdx.x & 7;
  const int qbase = (blockIdx.x >> 3) * 64;

  char* Kl = smem + khalf * 8192;
  char* Vl = smem + 16384 + khalf * 8192;
  float* kbf    = (float*)(smem + 32768);
  float* alphav = (float*)(smem + 33280);
  float* mM     = (float*)(smem + 33792);
  float* mL     = (float*)(smem + 34048);
  float* bC0    = (float*)(smem + 34304);
  float* bC1    = (float*)(smem + 34560);

  const int grow = qbase + qrw + lq;
  const float qs = mqg[batch * N_ + grow] ? 0.1803368801111204f : 0.0f;
  bfrag qf[4];
  {
    const float* Qp = qg + ((size_t)batch * N_ + grow) * D_ + lh * 8;
#pragma unroll
    for (int c = 0; c < 4; ++c) {
      float4 a = *(const float4*)(Qp + c * 16);
      float4 b = *(const float4*)(Qp + c * 16 + 4);
      FragU f;
      f.u[0] = pkbf(a.x * qs, a.y * qs);
      f.u[1] = pkbf(a.z * qs, a.w * qs);
      f.u[2] = pkbf(b.x * qs, b.y * qs);
      f.u[3] = pkbf(b.z * qs, b.w * qs);
      qf[c] = f.f;
    }
  }

  const int sid   = tid & 127;
  const int shalf = tid >> 7;

  f32x16 o0, o1;
#pragma unroll
  for (int i = 0; i < 16; ++i) { o0[i] = 0.f; o1[i] = 0.f; }
  float m2 = -1e30f, lsum = 0.f;

  for (int t = 0; t < 32; ++t) {
    __syncthreads();
    {
      const int kb0 = shalf * 2048 + t * 64;
      const float4* K4 = (const float4*)(kg + ((size_t)batch * M_ + kb0) * D_);
      const float4* V4 = (const float4*)(vg + ((size_t)batch * M_ + kb0) * D_);
      char* Ks = smem + shalf * 8192;
      char* Vs = smem + 16384 + shalf * 8192;
#pragma unroll
      for (int j = 0; j < 8; ++j) {
        int idx = sid + j * 128;
        float4 a = K4[idx];
        int row = idx >> 4, col = (idx & 15) << 2;
        *(uint2*)(Ks + swz((unsigned)(row * 128 + col * 2))) =
            make_uint2(pkbf(a.x, a.y), pkbf(a.z, a.w));
        float4 b = V4[idx];
        int vk = idx >> 4, vc = (idx & 15) << 2;
        *(unsigned short*)(Vs + swz((unsigned)((vc + 0) * 128 + vk * 2))) = bf1(b.x);
        *(unsigned short*)(Vs + swz((unsigned)((vc + 1) * 128 + vk * 2))) = bf1(b.y);
        *(unsigned short*)(Vs + swz((unsigned)((vc + 2) * 128 + vk * 2))) = bf1(b.z);
        *(unsigned short*)(Vs + swz((unsigned)((vc + 3) * 128 + vk * 2))) = bf1(b.w);
      }
      if (sid < 64)
        kbf[shalf * 64 + sid] = mkg[batch * M_ + kb0 + sid] ? 0.f : -1e30f;
    }
    __syncthreads();

    f32x16 s0, s1;
#pragma unroll
    for (int i = 0; i < 16; ++i) { s0[i] = 0.f; s1[i] = 0.f; }
#pragma unroll
    for (int c = 0; c < 4; ++c) {
      bfrag kf0 = *(const bfrag*)(Kl + swz((unsigned)(lq * 128 + (c * 16 + lh * 8) * 2)));
      bfrag kf1 = *(const bfrag*)(Kl + swz((unsigned)((32 + lq) * 128 + (c * 16 + lh * 8) * 2)));
      s0 = __builtin_amdgcn_mfma_f32_32x32x16_bf16(kf0, qf[c], s0, 0, 0, 0);
      s1 = __builtin_amdgcn_mfma_f32_32x32x16_bf16(kf1, qf[c], s1, 0, 0, 0);
    }

    const float* kbh = kbf + khalf * 64;
    float mx = -1e30f;
#pragma unroll
    for (int g = 0; g < 4; ++g) {
      f32x4 b0 = *(const f32x4*)(kbh + g * 8 + 4 * lh);
      f32x4 b1 = *(const f32x4*)(kbh + 32 + g * 8 + 4 * lh);
#pragma unroll
      for (int r = 0; r < 4; ++r) {
        s0[g * 4 + r] += b0[r];
        s1[g * 4 + r] += b1[r];
        mx = fmaxf(mx, fmaxf(s0[g * 4 + r], s1[g * 4 + r]));
      }
    }
    mx = fmaxf(mx, __shfl_xor(mx, 32));

    if (__any(mx > m2 + 8.f)) {
      float mn = fmaxf(m2, mx);
      float al = __builtin_amdgcn_exp2f(m2 - mn);
      if (lane < 32) alphav[wid * 32 + lane] = al;
      asm volatile("s_waitcnt lgkmcnt(0)" ::: "memory");
#pragma unroll
      for (int g = 0; g < 4; ++g) {
        f32x4 av = *(const f32x4*)(alphav + wid * 32 + g * 8 + 4 * lh);
#pragma unroll
        for (int r = 0; r < 4; ++r) { o0[g * 4 + r] *= av[r]; o1[g * 4 + r] *= av[r]; }
      }
      lsum *= al;
      m2 = mn;
    }

    float ps = 0.f;
#pragma unroll
    for (int i = 0; i < 16; ++i) {
      float p0 = __builtin_amdgcn_exp2f(s0[i] - m2);
      float p1 = __builtin_amdgcn_exp2f(s1[i] - m2);
      s0[i] = p0; s1[i] = p1;
      ps += p0 + p1;
    }
    ps += __shfl_xor(ps, 32);
    lsum += ps;

#pragma unroll
    for (int mc = 0; mc < 4; ++mc) {
      unsigned int c01, c23, c45, c67;
      {
        const int Rb = (mc & 1) * 8;
        if (mc < 2) {
          c01 = pkbf(s0[Rb + 0], s0[Rb + 1]); c23 = pkbf(s0[Rb + 2], s0[Rb + 3]);
          c45 = pkbf(s0[Rb + 4], s0[Rb + 5]); c67 = pkbf(s0[Rb + 6], s0[Rb + 7]);
        } else {
          c01 = pkbf(s1[Rb + 0], s1[Rb + 1]); c23 = pkbf(s1[Rb + 2], s1[Rb + 3]);
          c45 = pkbf(s1[Rb + 4], s1[Rb + 5]); c67 = pkbf(s1[Rb + 6], s1[Rb + 7]);
        }
      }
      unsigned int t01 = (unsigned int)__shfl_xor((int)c01, 32);
      unsigned int t23 = (unsigned int)__shfl_xor((int)c23, 32);
      unsigned int t45 = (unsigned int)__shfl_xor((int)c45, 32);
      unsigned int t67 = (unsigned int)__shfl_xor((int)c67, 32);
      FragU pa;
      pa.u[0] = lh ? t45 : c01;
      pa.u[1] = lh ? t67 : c23;
      pa.u[2] = lh ? c45 : t01;
      pa.u[3] = lh ? c67 : t23;
      bfrag vf0 = *(const bfrag*)(Vl + swz((unsigned)(lq * 128 + (mc * 16 + lh * 8) * 2)));
      bfrag vf1 = *(const bfrag*)(Vl + swz((unsigned)((32 + lq) * 128 + (mc * 16 + lh * 8) * 2)));
      o0 = __builtin_amdgcn_mfma_f32_32x32x16_bf16(pa.f, vf0, o0, 0, 0, 0);
      o1 = __builtin_amdgcn_mfma_f32_32x32x16_bf16(pa.f, vf1, o1, 0, 0, 0);
    }
  }

  __syncthreads();
  float* Omg = (float*)smem;
  if (khalf == 1) {
    const int w = wid & 1;
    if (lane < 32) { mM[w * 32 + lane] = m2; mL[w * 32 + lane] = lsum; }
#pragma unroll
    for (int r = 0; r < 16; ++r) {
      const int row = (r & 3) + 8 * (r >> 2) + 4 * lh;
      Omg[w * 2048 + row * 64 + lq]      = o0[r];
      Omg[w * 2048 + row * 64 + 32 + lq] = o1[r];
    }
  }
  __syncthreads();
  if (khalf == 0) {
    const int w = wid & 1;
    float m1 = mM[w * 32 + lq], l1 = mL[w * 32 + lq];
    float msf = fmaxf(m2, m1);
    float c0 = __builtin_amdgcn_exp2f(m2 - msf);
    float c1 = __builtin_amdgcn_exp2f(m1 - msf);
    float il = 1.f / (lsum * c0 + l1 * c1);
    if (lane < 32) { bC0[w * 32 + lane] = c0 * il; bC1[w * 32 + lane] = c1 * il; }
    asm volatile("s_waitcnt lgkmcnt(0)" ::: "memory");
    float* outp = outg + ((size_t)batch * N_ + qbase + qrw) * 64;
#pragma unroll
    for (int g = 0; g < 4; ++g) {
      f32x4 a0 = *(const f32x4*)(bC0 + w * 32 + g * 8 + 4 * lh);
      f32x4 a1 = *(const f32x4*)(bC1 + w * 32 + g * 8 + 4 * lh);
#pragma unroll
      for (int rr = 0; rr < 4; ++rr) {
        const int r = g * 4 + rr;
        const int row = rr + 8 * g + 4 * lh;
        float r0 = o0[r] * a0[rr] + Omg[w * 2048 + row * 64 + lq]      * a1[rr];
        float r1 = o1[r] * a0[rr] + Omg[w * 2048 + row * 64 + 32 + lq] * a1[rr];
        outp[(size_t)row * 64 + lq]      = r0;
        outp[(size_t)row * 64 + 32 + lq] = r1;
      }
    }
  }
}

extern "C" void kernel_launch(void* const* d_in, const int* in_sizes, int n_in,
                              void* d_out, int out_size, void* d_ws, size_t ws_size,
                              hipStream_t stream) {
  const float* q  = (const float*)d_in[0];
  const float* k  = (const float*)d_in[1];
  const float* v  = (const float*)d_in[2];
  const int*   mq = (const int*)d_in[3];
  const int*   mk = (const int*)d_in[4];
  float* out = (float*)d_out;

  const size_t kws_off = 0;
  const size_t vws_off = (size_t)B_ * 64 * 8192;           // 4 MiB
  const size_t bws_off = vws_off * 2;                      // 8 MiB
  const size_t need    = bws_off + (size_t)B_ * M_ * 4;    // +128 KiB

  if (ws_size >= need) {
    char*  kws = (char*)d_ws + kws_off;
    char*  vws = (char*)d_ws + vws_off;
    float* bws = (float*)((char*)d_ws + bws_off);
    attn_prepass<<<dim3(2048), dim3(256), 0, stream>>>(k, v, mk, kws, vws, bws);
    attn_main<<<dim3(512), dim3(256), 0, stream>>>(q, mq, kws, vws, bws, out);
  } else {
    attn_fused<<<dim3(512), dim3(256), 0, stream>>>(q, k, v, mq, mk, out);
  }
}

// Round 3
// 74.679 us; speedup vs baseline: 1.7760x; 1.0915x over previous
//
#include <hip/hip_runtime.h>

// Masked attention, b=8 n=m=4096 d=dv=64, f32 in/out.
// R3: prepass packs K and V^T in per-lane MFMA-fragment order; main kernel is
// barrier-free (no LDS in the K-loop), 4-way key split, frags loaded
// global->VGPR directly (K/V are L2-resident per XCD via batch=bid&7 swizzle).

#define B_ 8
#define N_ 4096
#define M_ 4096
#define D_ 64

typedef __attribute__((ext_vector_type(8))) __bf16 bfrag;
typedef __attribute__((ext_vector_type(16))) float f32x16;
typedef __attribute__((ext_vector_type(4))) float f32x4;

union FragU { bfrag f; unsigned int u[4]; };

__device__ __forceinline__ unsigned int pkbf(float lo, float hi) {
  unsigned short a = __builtin_bit_cast(unsigned short, (__bf16)lo);
  unsigned short b = __builtin_bit_cast(unsigned short, (__bf16)hi);
  return ((unsigned int)b << 16) | (unsigned int)a;
}
__device__ __forceinline__ unsigned short bf1(float x) {
  return __builtin_bit_cast(unsigned short, (__bf16)x);
}

// ---------------- prepass: pack fragment-order bf16 images ----------------
// kpack chunk id c0 = ((batch*64+tile)*8 + c*2 + f)*64 + lane  -> 16B at c0*16
//   value: 8 bf16 of K[batch][tile*64 + f*32 + (lane&31)][c*16 + (lane>>5)*8 + 0..7]
// vpack chunk id same shape with (mc, f):
//   value: 8 bf16 of V[batch][tile*64 + mc*16 + (lane>>5)*8 + j][f*32 + (lane&31)]
// bws: [8][4096] f32 key bias (0 / -1e30)
__global__ void attn_prepass(const float* __restrict__ kg, const float* __restrict__ vg,
                             const int* __restrict__ mkg, char* __restrict__ kpack,
                             char* __restrict__ vpack, float* __restrict__ bws)
{
  const int bid = blockIdx.x, tid = threadIdx.x;
  if (bid < 1024) {
    const unsigned c0 = bid * 256 + tid;     // 0..262143
    const int lane = c0 & 63;
    const unsigned u = c0 >> 6;
    const int f = u & 1, c = (u >> 1) & 3, tile = (u >> 3) & 63, batch = u >> 9;
    const int lq = lane & 31, lh = lane >> 5;
    const int row = tile * 64 + f * 32 + lq;
    const float* src = kg + (((size_t)batch * M_ + row) * D_ + c * 16 + lh * 8);
    float4 a = ((const float4*)src)[0], b = ((const float4*)src)[1];
    uint4 o;
    o.x = pkbf(a.x, a.y); o.y = pkbf(a.z, a.w);
    o.z = pkbf(b.x, b.y); o.w = pkbf(b.z, b.w);
    *(uint4*)(kpack + (size_t)c0 * 16) = o;
    if (tid < 32) {
      const int i = bid * 32 + tid;          // 0..32767
      bws[i] = mkg[i] ? 0.f : -1e30f;
    }
  } else {
    const unsigned c0 = (bid - 1024) * 256 + tid;
    const int lane = c0 & 63;
    const unsigned u = c0 >> 6;
    const int f = u & 1, mc = (u >> 1) & 3, tile = (u >> 3) & 63, batch = u >> 9;
    const int lq = lane & 31, lh = lane >> 5;
    const int key0 = tile * 64 + mc * 16 + lh * 8;
    const int dv = f * 32 + lq;
    const float* base = vg + (((size_t)batch * M_ + key0) * D_ + dv);
    unsigned short h[8];
#pragma unroll
    for (int j = 0; j < 8; ++j) h[j] = bf1(base[(size_t)j * D_]);
    uint4 o;
    o.x = (unsigned)h[0] | ((unsigned)h[1] << 16);
    o.y = (unsigned)h[2] | ((unsigned)h[3] << 16);
    o.z = (unsigned)h[4] | ((unsigned)h[5] << 16);
    o.w = (unsigned)h[6] | ((unsigned)h[7] << 16);
    *(uint4*)(vpack + (size_t)c0 * 16) = o;
  }
}

// ---------------- main kernel: barrier-free K-loop ----------------
// Block = 32 q-rows, 4 waves = 4 key-quarters (16 tiles each). Merge in LDS.
// LDS: 0..16384 Oacc A/B; 16384 mArr[4][32]; 16896 lArr[4][32];
//      17408 alphav[4][32]; 17920 Minv[32]; 18048 Ilv[32]
__global__ __launch_bounds__(256, 3) void attn_main(
    const float* __restrict__ qg, const int* __restrict__ mqg,
    const char* __restrict__ kpack, const char* __restrict__ vpack,
    const float* __restrict__ bws, float* __restrict__ outg)
{
  __shared__ alignas(16) char smem[18176];
  const int tid  = threadIdx.x;
  const int lane = tid & 63;
  const int lq   = lane & 31;
  const int lh   = lane >> 5;
  const int wid  = tid >> 6;            // key quarter
  const int batch = blockIdx.x & 7;     // batch == XCD for L2 locality
  const int qbase = (blockIdx.x >> 3) * 32;

  float* mArr   = (float*)(smem + 16384);
  float* lArr   = (float*)(smem + 16896);
  float* alphav = (float*)(smem + 17408);
  float* Minv   = (float*)(smem + 17920);
  float* Ilv    = (float*)(smem + 18048);

  // ---- Q frags (rows qbase+lq, shared by all 4 waves), pre-scaled ----
  const int grow = qbase + lq;
  const float qs = mqg[batch * N_ + grow] ? 0.1803368801111204f : 0.0f;
  bfrag qf[4];
  {
    const float* Qp = qg + ((size_t)batch * N_ + grow) * D_ + lh * 8;
#pragma unroll
    for (int c = 0; c < 4; ++c) {
      float4 a = *(const float4*)(Qp + c * 16);
      float4 b = *(const float4*)(Qp + c * 16 + 4);
      FragU f;
      f.u[0] = pkbf(a.x * qs, a.y * qs);
      f.u[1] = pkbf(a.z * qs, a.w * qs);
      f.u[2] = pkbf(b.x * qs, b.y * qs);
      f.u[3] = pkbf(b.z * qs, b.w * qs);
      qf[c] = f.f;
    }
  }

  f32x16 o0, o1;
#pragma unroll
  for (int i = 0; i < 16; ++i) { o0[i] = 0.f; o1[i] = 0.f; }
  float m2 = -1e30f, lsum = 0.f;

  const float* bbase = bws + batch * M_ + wid * 1024;

  for (int t16 = 0; t16 < 16; ++t16) {
    const int tile = wid * 16 + t16;
    const size_t tb = (size_t)(batch * 64 + tile) * 8192 + (size_t)lane * 16;

    // ---- K frags ----
    bfrag kf[4][2];
#pragma unroll
    for (int c = 0; c < 4; ++c) {
      kf[c][0] = *(const bfrag*)(kpack + tb + (c * 2 + 0) * 1024);
      kf[c][1] = *(const bfrag*)(kpack + tb + (c * 2 + 1) * 1024);
    }
    // ---- V frags (issued early; consumed after softmax) ----
    bfrag vf[4][2];
#pragma unroll
    for (int mc = 0; mc < 4; ++mc) {
      vf[mc][0] = *(const bfrag*)(vpack + tb + (mc * 2 + 0) * 1024);
      vf[mc][1] = *(const bfrag*)(vpack + tb + (mc * 2 + 1) * 1024);
    }

    // ---- swapped QK^T ----
    f32x16 s0, s1;
#pragma unroll
    for (int i = 0; i < 16; ++i) { s0[i] = 0.f; s1[i] = 0.f; }
    __builtin_amdgcn_s_setprio(1);
#pragma unroll
    for (int c = 0; c < 4; ++c) {
      s0 = __builtin_amdgcn_mfma_f32_32x32x16_bf16(kf[c][0], qf[c], s0, 0, 0, 0);
      s1 = __builtin_amdgcn_mfma_f32_32x32x16_bf16(kf[c][1], qf[c], s1, 0, 0, 0);
    }
    __builtin_amdgcn_s_setprio(0);

    // ---- key bias + row max ----
    const float* bb = bbase + t16 * 64;
    float mx = -1e30f;
#pragma unroll
    for (int g = 0; g < 4; ++g) {
      f32x4 b0 = *(const f32x4*)(bb + g * 8 + 4 * lh);
      f32x4 b1 = *(const f32x4*)(bb + 32 + g * 8 + 4 * lh);
#pragma unroll
      for (int r = 0; r < 4; ++r) {
        s0[g * 4 + r] += b0[r];
        s1[g * 4 + r] += b1[r];
        mx = fmaxf(mx, fmaxf(s0[g * 4 + r], s1[g * 4 + r]));
      }
    }
    mx = fmaxf(mx, __shfl_xor(mx, 32));

    // ---- defer-max rescale (THR=8 log2 units); same-wave LDS bounce ----
    if (__any(mx > m2 + 8.f)) {
      float mn = fmaxf(m2, mx);
      float al = __builtin_amdgcn_exp2f(m2 - mn);
      if (lane < 32) alphav[wid * 32 + lane] = al;
      asm volatile("s_waitcnt lgkmcnt(0)" ::: "memory");
#pragma unroll
      for (int g = 0; g < 4; ++g) {
        f32x4 av = *(const f32x4*)(alphav + wid * 32 + g * 8 + 4 * lh);
#pragma unroll
        for (int r = 0; r < 4; ++r) { o0[g * 4 + r] *= av[r]; o1[g * 4 + r] *= av[r]; }
      }
      lsum *= al;
      m2 = mn;
    }

    // ---- p = exp2(logit - m), running sum ----
    float ps = 0.f;
#pragma unroll
    for (int i = 0; i < 16; ++i) {
      float p0 = __builtin_amdgcn_exp2f(s0[i] - m2);
      float p1 = __builtin_amdgcn_exp2f(s1[i] - m2);
      s0[i] = p0; s1[i] = p1;
      ps += p0 + p1;
    }
    ps += __shfl_xor(ps, 32);
    lsum += ps;

    // ---- P·V ----
#pragma unroll
    for (int mc = 0; mc < 4; ++mc) {
      unsigned int c01, c23, c45, c67;
      {
        const int Rb = (mc & 1) * 8;
        if (mc < 2) {
          c01 = pkbf(s0[Rb + 0], s0[Rb + 1]); c23 = pkbf(s0[Rb + 2], s0[Rb + 3]);
          c45 = pkbf(s0[Rb + 4], s0[Rb + 5]); c67 = pkbf(s0[Rb + 6], s0[Rb + 7]);
        } else {
          c01 = pkbf(s1[Rb + 0], s1[Rb + 1]); c23 = pkbf(s1[Rb + 2], s1[Rb + 3]);
          c45 = pkbf(s1[Rb + 4], s1[Rb + 5]); c67 = pkbf(s1[Rb + 6], s1[Rb + 7]);
        }
      }
      unsigned int t01 = (unsigned int)__shfl_xor((int)c01, 32);
      unsigned int t23 = (unsigned int)__shfl_xor((int)c23, 32);
      unsigned int t45 = (unsigned int)__shfl_xor((int)c45, 32);
      unsigned int t67 = (unsigned int)__shfl_xor((int)c67, 32);
      FragU pa;
      pa.u[0] = lh ? t45 : c01;
      pa.u[1] = lh ? t67 : c23;
      pa.u[2] = lh ? c45 : t01;
      pa.u[3] = lh ? c67 : t23;
      __builtin_amdgcn_s_setprio(1);
      o0 = __builtin_amdgcn_mfma_f32_32x32x16_bf16(pa.f, vf[mc][0], o0, 0, 0, 0);
      o1 = __builtin_amdgcn_mfma_f32_32x32x16_bf16(pa.f, vf[mc][1], o1, 0, 0, 0);
      __builtin_amdgcn_s_setprio(0);
    }
  }

  // ---- 4-way merge ----
  if (lane < 32) { mArr[wid * 32 + lane] = m2; lArr[wid * 32 + lane] = lsum; }
  __syncthreads();
  {
    // per-lane (q = lq) global stats; all waves compute, wave 0 publishes
    float M = -1e30f;
#pragma unroll
    for (int w = 0; w < 4; ++w) M = fmaxf(M, mArr[w * 32 + lq]);
    float lt = 0.f;
#pragma unroll
    for (int w = 0; w < 4; ++w)
      lt += lArr[w * 32 + lq] * __builtin_amdgcn_exp2f(mArr[w * 32 + lq] - M);
    float il = 1.f / lt;
    if (wid == 0 && lane < 32) { Minv[lane] = M; Ilv[lane] = il; }
  }
  __syncthreads();
  // scale own partial by exp2(m_w - M) / l_tot, row-indexed
#pragma unroll
  for (int g = 0; g < 4; ++g) {
    f32x4 mw = *(const f32x4*)(mArr + wid * 32 + g * 8 + 4 * lh);
    f32x4 Mv = *(const f32x4*)(Minv + g * 8 + 4 * lh);
    f32x4 Iv = *(const f32x4*)(Ilv + g * 8 + 4 * lh);
#pragma unroll
    for (int rr = 0; rr < 4; ++rr) {
      float sc = __builtin_amdgcn_exp2f(mw[rr] - Mv[rr]) * Iv[rr];
      o0[g * 4 + rr] *= sc;
      o1[g * 4 + rr] *= sc;
    }
  }
  // accumulate: waves 0,1 write A,B; waves 2,3 add
  float* A = (float*)smem;          // [32][64]
  float* Bb = (float*)smem + 2048;  // [32][64]
  float* dst = (wid & 1) ? Bb : A;
  if (wid < 2) {
#pragma unroll
    for (int r = 0; r < 16; ++r) {
      const int row = (r & 3) + 8 * (r >> 2) + 4 * lh;
      dst[row * 64 + lq]      = o0[r];
      dst[row * 64 + 32 + lq] = o1[r];
    }
  }
  __syncthreads();
  if (wid >= 2) {
#pragma unroll
    for (int r = 0; r < 16; ++r) {
      const int row = (r & 3) + 8 * (r >> 2) + 4 * lh;
      dst[row * 64 + lq]      += o0[r];
      dst[row * 64 + 32 + lq] += o1[r];
    }
  }
  __syncthreads();
  // combined store: 32x64 f32, coalesced
  {
    float* op = outg + ((size_t)batch * N_ + qbase) * 64;
    const int i = tid * 8;
    f32x4 a0 = *(const f32x4*)(A + i),     b0 = *(const f32x4*)(Bb + i);
    f32x4 a1 = *(const f32x4*)(A + i + 4), b1 = *(const f32x4*)(Bb + i + 4);
#pragma unroll
    for (int r = 0; r < 4; ++r) { a0[r] += b0[r]; a1[r] += b1[r]; }
    *(f32x4*)(op + i)     = a0;
    *(f32x4*)(op + i + 4) = a1;
  }
}

// ---------------- fallback (R1, verified): used if ws too small ----------------
__device__ __forceinline__ unsigned int swz(unsigned int byte) {
  return byte ^ (((byte >> 7) & 7) << 4);
}

__global__ __launch_bounds__(256, 2) void attn_fused(
    const float* __restrict__ qg, const float* __restrict__ kg,
    const float* __restrict__ vg, const int* __restrict__ mqg,
    const int* __restrict__ mkg, float* __restrict__ outg)
{
  __shared__ alignas(16) char smem[35072];
  const int tid  = threadIdx.x;
  const int lane = tid & 63;
  const int lq   = lane & 31;
  const int lh   = lane >> 5;
  const int wid  = tid >> 6;
  const int khalf = wid >> 1;
  const int qrw  = (wid & 1) * 32;
  const int batch = blockIdx.x & 7;
  const int qbase = (blockIdx.x >> 3) * 64;

  char* Kl = smem + khalf * 8192;
  char* Vl = smem + 16384 + khalf * 8192;
  float* kbf    = (float*)(smem + 32768);
  float* alphav = (float*)(smem + 33280);
  float* mM     = (float*)(smem + 33792);
  float* mL     = (float*)(smem + 34048);
  float* bC0    = (float*)(smem + 34304);
  float* bC1    = (float*)(smem + 34560);

  const int grow = qbase + qrw + lq;
  const float qs = mqg[batch * N_ + grow] ? 0.1803368801111204f : 0.0f;
  bfrag qf[4];
  {
    const float* Qp = qg + ((size_t)batch * N_ + grow) * D_ + lh * 8;
#pragma unroll
    for (int c = 0; c < 4; ++c) {
      float4 a = *(const float4*)(Qp + c * 16);
      float4 b = *(const float4*)(Qp + c * 16 + 4);
      FragU f;
      f.u[0] = pkbf(a.x * qs, a.y * qs);
      f.u[1] = pkbf(a.z * qs, a.w * qs);
      f.u[2] = pkbf(b.x * qs, b.y * qs);
      f.u[3] = pkbf(b.z * qs, b.w * qs);
      qf[c] = f.f;
    }
  }

  const int sid   = tid & 127;
  const int shalf = tid >> 7;

  f32x16 o0, o1;
#pragma unroll
  for (int i = 0; i < 16; ++i) { o0[i] = 0.f; o1[i] = 0.f; }
  float m2 = -1e30f, lsum = 0.f;

  for (int t = 0; t < 32; ++t) {
    __syncthreads();
    {
      const int kb0 = shalf * 2048 + t * 64;
      const float4* K4 = (const float4*)(kg + ((size_t)batch * M_ + kb0) * D_);
      const float4* V4 = (const float4*)(vg + ((size_t)batch * M_ + kb0) * D_);
      char* Ks = smem + shalf * 8192;
      char* Vs = smem + 16384 + shalf * 8192;
#pragma unroll
      for (int j = 0; j < 8; ++j) {
        int idx = sid + j * 128;
        float4 a = K4[idx];
        int row = idx >> 4, col = (idx & 15) << 2;
        *(uint2*)(Ks + swz((unsigned)(row * 128 + col * 2))) =
            make_uint2(pkbf(a.x, a.y), pkbf(a.z, a.w));
        float4 b = V4[idx];
        int vk = idx >> 4, vc = (idx & 15) << 2;
        *(unsigned short*)(Vs + swz((unsigned)((vc + 0) * 128 + vk * 2))) = bf1(b.x);
        *(unsigned short*)(Vs + swz((unsigned)((vc + 1) * 128 + vk * 2))) = bf1(b.y);
        *(unsigned short*)(Vs + swz((unsigned)((vc + 2) * 128 + vk * 2))) = bf1(b.z);
        *(unsigned short*)(Vs + swz((unsigned)((vc + 3) * 128 + vk * 2))) = bf1(b.w);
      }
      if (sid < 64)
        kbf[shalf * 64 + sid] = mkg[batch * M_ + kb0 + sid] ? 0.f : -1e30f;
    }
    __syncthreads();

    f32x16 s0, s1;
#pragma unroll
    for (int i = 0; i < 16; ++i) { s0[i] = 0.f; s1[i] = 0.f; }
#pragma unroll
    for (int c = 0; c < 4; ++c) {
      bfrag kf0 = *(const bfrag*)(Kl + swz((unsigned)(lq * 128 + (c * 16 + lh * 8) * 2)));
      bfrag kf1 = *(const bfrag*)(Kl + swz((unsigned)((32 + lq) * 128 + (c * 16 + lh * 8) * 2)));
      s0 = __builtin_amdgcn_mfma_f32_32x32x16_bf16(kf0, qf[c], s0, 0, 0, 0);
      s1 = __builtin_amdgcn_mfma_f32_32x32x16_bf16(kf1, qf[c], s1, 0, 0, 0);
    }

    const float* kbh = kbf + khalf * 64;
    float mx = -1e30f;
#pragma unroll
    for (int g = 0; g < 4; ++g) {
      f32x4 b0 = *(const f32x4*)(kbh + g * 8 + 4 * lh);
      f32x4 b1 = *(const f32x4*)(kbh + 32 + g * 8 + 4 * lh);
#pragma unroll
      for (int r = 0; r < 4; ++r) {
        s0[g * 4 + r] += b0[r];
        s1[g * 4 + r] += b1[r];
        mx = fmaxf(mx, fmaxf(s0[g * 4 + r], s1[g * 4 + r]));
      }
    }
    mx = fmaxf(mx, __shfl_xor(mx, 32));

    if (__any(mx > m2 + 8.f)) {
      float mn = fmaxf(m2, mx);
      float al = __builtin_amdgcn_exp2f(m2 - mn);
      if (lane < 32) alphav[wid * 32 + lane] = al;
      asm volatile("s_waitcnt lgkmcnt(0)" ::: "memory");
#pragma unroll
      for (int g = 0; g < 4; ++g) {
        f32x4 av = *(const f32x4*)(alphav + wid * 32 + g * 8 + 4 * lh);
#pragma unroll
        for (int r = 0; r < 4; ++r) { o0[g * 4 + r] *= av[r]; o1[g * 4 + r] *= av[r]; }
      }
      lsum *= al;
      m2 = mn;
    }

    float ps = 0.f;
#pragma unroll
    for (int i = 0; i < 16; ++i) {
      float p0 = __builtin_amdgcn_exp2f(s0[i] - m2);
      float p1 = __builtin_amdgcn_exp2f(s1[i] - m2);
      s0[i] = p0; s1[i] = p1;
      ps += p0 + p1;
    }
    ps += __shfl_xor(ps, 32);
    lsum += ps;

#pragma unroll
    for (int mc = 0; mc < 4; ++mc) {
      unsigned int c01, c23, c45, c67;
      {
        const int Rb = (mc & 1) * 8;
        if (mc < 2) {
          c01 = pkbf(s0[Rb + 0], s0[Rb + 1]); c23 = pkbf(s0[Rb + 2], s0[Rb + 3]);
          c45 = pkbf(s0[Rb + 4], s0[Rb + 5]); c67 = pkbf(s0[Rb + 6], s0[Rb + 7]);
        } else {
          c01 = pkbf(s1[Rb + 0], s1[Rb + 1]); c23 = pkbf(s1[Rb + 2], s1[Rb + 3]);
          c45 = pkbf(s1[Rb + 4], s1[Rb + 5]); c67 = pkbf(s1[Rb + 6], s1[Rb + 7]);
        }
      }
      unsigned int t01 = (unsigned int)__shfl_xor((int)c01, 32);
      unsigned int t23 = (unsigned int)__shfl_xor((int)c23, 32);
      unsigned int t45 = (unsigned int)__shfl_xor((int)c45, 32);
      unsigned int t67 = (unsigned int)__shfl_xor((int)c67, 32);
      FragU pa;
      pa.u[0] = lh ? t45 : c01;
      pa.u[1] = lh ? t67 : c23;
      pa.u[2] = lh ? c45 : t01;
      pa.u[3] = lh ? c67 : t23;
      bfrag vf0 = *(const bfrag*)(Vl + swz((unsigned)(lq * 128 + (mc * 16 + lh * 8) * 2)));
      bfrag vf1 = *(const bfrag*)(Vl + swz((unsigned)((32 + lq) * 128 + (mc * 16 + lh * 8) * 2)));
      o0 = __builtin_amdgcn_mfma_f32_32x32x16_bf16(pa.f, vf0, o0, 0, 0, 0);
      o1 = __builtin_amdgcn_mfma_f32_32x32x16_bf16(pa.f, vf1, o1, 0, 0, 0);
    }
  }

  __syncthreads();
  float* Omg = (float*)smem;
  if (khalf == 1) {
    const int w = wid & 1;
    if (lane < 32) { mM[w * 32 + lane] = m2; mL[w * 32 + lane] = lsum; }
#pragma unroll
    for (int r = 0; r < 16; ++r) {
      const int row = (r & 3) + 8 * (r >> 2) + 4 * lh;
      Omg[w * 2048 + row * 64 + lq]      = o0[r];
      Omg[w * 2048 + row * 64 + 32 + lq] = o1[r];
    }
  }
  __syncthreads();
  if (khalf == 0) {
    const int w = wid & 1;
    float m1 = mM[w * 32 + lq], l1 = mL[w * 32 + lq];
    float msf = fmaxf(m2, m1);
    float c0 = __builtin_amdgcn_exp2f(m2 - msf);
    float c1 = __builtin_amdgcn_exp2f(m1 - msf);
    float il = 1.f / (lsum * c0 + l1 * c1);
    if (lane < 32) { bC0[w * 32 + lane] = c0 * il; bC1[w * 32 + lane] = c1 * il; }
    asm volatile("s_waitcnt lgkmcnt(0)" ::: "memory");
    float* outp = outg + ((size_t)batch * N_ + qbase + qrw) * 64;
#pragma unroll
    for (int g = 0; g < 4; ++g) {
      f32x4 a0 = *(const f32x4*)(bC0 + w * 32 + g * 8 + 4 * lh);
      f32x4 a1 = *(const f32x4*)(bC1 + w * 32 + g * 8 + 4 * lh);
#pragma unroll
      for (int rr = 0; rr < 4; ++rr) {
        const int r = g * 4 + rr;
        const int row = rr + 8 * g + 4 * lh;
        float r0 = o0[r] * a0[rr] + Omg[w * 2048 + row * 64 + lq]      * a1[rr];
        float r1 = o1[r] * a0[rr] + Omg[w * 2048 + row * 64 + 32 + lq] * a1[rr];
        outp[(size_t)row * 64 + lq]      = r0;
        outp[(size_t)row * 64 + 32 + lq] = r1;
      }
    }
  }
}

extern "C" void kernel_launch(void* const* d_in, const int* in_sizes, int n_in,
                              void* d_out, int out_size, void* d_ws, size_t ws_size,
                              hipStream_t stream) {
  const float* q  = (const float*)d_in[0];
  const float* k  = (const float*)d_in[1];
  const float* v  = (const float*)d_in[2];
  const int*   mq = (const int*)d_in[3];
  const int*   mk = (const int*)d_in[4];
  float* out = (float*)d_out;

  const size_t kp_off = 0;
  const size_t vp_off = (size_t)B_ * 64 * 8192;            // 4 MiB
  const size_t bw_off = vp_off * 2;                        // 8 MiB
  const size_t need   = bw_off + (size_t)B_ * M_ * 4;      // +128 KiB

  if (ws_size >= need) {
    char*  kpack = (char*)d_ws + kp_off;
    char*  vpack = (char*)d_ws + vp_off;
    float* bws   = (float*)((char*)d_ws + bw_off);
    attn_prepass<<<dim3(2048), dim3(256), 0, stream>>>(k, v, mk, kpack, vpack, bws);
    attn_main<<<dim3(1024), dim3(256), 0, stream>>>(q, mq, kpack, vpack, bws, out);
  } else {
    attn_fused<<<dim3(512), dim3(256), 0, stream>>>(q, k, v, mq, mk, out);
  }
}